// Round 4
// baseline (3596.507 us; speedup 1.0000x reference)
//
#include <hip/hip_runtime.h>
#include <hip/hip_bf16.h>
#include <cstdint>
#include <cstddef>

// Problem constants
#define BATCH_  8
#define CMID_   128
#define A1_     36864     // 64*9*64  (cw1 floats per (b,p))
#define ATOT_   110592    // A1 + 64*9*128
#define NPX_    524288.0f // 8*256*256 elements per channel for BN stats

// ---------------- helpers: u-buffer store/load (fp32 primary, bf16 fallback) --

__device__ __forceinline__ float loadU(const float* p) { return *p; }
__device__ __forceinline__ float loadU(const __hip_bfloat16* p) { return __bfloat162float(*p); }

__device__ __forceinline__ void store16(float* p, const float* v) {
    float4* q = reinterpret_cast<float4*>(p);
    q[0] = make_float4(v[0],  v[1],  v[2],  v[3]);
    q[1] = make_float4(v[4],  v[5],  v[6],  v[7]);
    q[2] = make_float4(v[8],  v[9],  v[10], v[11]);
    q[3] = make_float4(v[12], v[13], v[14], v[15]);
}
__device__ __forceinline__ void store16(__hip_bfloat16* p, const float* v) {
    #pragma unroll
    for (int i = 0; i < 16; i++) p[i] = __float2bfloat16(v[i]);
}

// ---------------- zero the stats area (harness poisons ws with 0xAA) ---------

__global__ void zero_kernel(float* __restrict__ p, int n) {
    int i = blockIdx.x * blockDim.x + threadIdx.x;
    if (i < n) p[i] = 0.0f;
}

// ---------------- fused conv (shared-half + patch-half) ----------------------
// Grid: 2048 blocks = B(8) * P(64) * G(4 oc-groups of 32).
//   g=0,1 -> shared conv (w1/w2), output channels g*32..g*32+31
//   g=2,3 -> per-(b,p) dynamic conv (conv_weights), channels 64..127
// Block: 512 threads. Thread (og=tid>>6, pg=tid&63):
//   computes acc[4 oc][16 px]; pixel group pg -> (row=pg>>1, half-row xh=pg&1).
// K-reduction chunked by 8 input channels staged in LDS.
// L2=false: input = x (fp32), output = u (raw pre-BN) + BN sums.
// L2=true : input = u with on-the-fly BN+ReLU (scale/shift), output = v (raw) + sums.
//
// LDS note: input-tile b128 reads have start-bank (4*row+16*xh)%32 -> 8 lanes
// per 4-word bank-group with distinct addresses: same histogram as the m134
// conflict-free b128 reference pattern (~85 B/cyc). Weight reads wave-uniform
// (broadcast). Estimated ~23k LDS-pipe vs ~37k VALU cycles/chunk/CU -> VALU-bound.
// Occupancy: ~48.4 KiB LDS, launch_bounds(512,4) -> 2 blocks/CU, VGPR<=128.

template<int CIN, bool L2, typename UT>
__global__ __launch_bounds__(512, 4) void conv_kernel(
    const float* __restrict__ xin,
    const UT*    __restrict__ uin,
    const float* __restrict__ wsh,       // w1 or w2: [64][CIN][3][3]
    const float* __restrict__ cw,        // conv_weights base [B][64][ATOT_]
    const float* __restrict__ scale_in,  // L2 only: [128]
    const float* __restrict__ shift_in,  // L2 only: [128]
    UT*    __restrict__ uout,            // L1 output
    float* __restrict__ vout,            // L2 output
    float* __restrict__ sums)            // [0..128) sum, [128..256) sumsq
{
    constexpr int CH = 8;                 // cin chunk
    __shared__ float lds_in[CH * 34 * 36];   // padded row stride 36 (16B-aligned rows)
    __shared__ float lds_w[CH * 9 * 32];     // [ic][k][oc] -> oc fastest
    __shared__ float lds_sc[CIN], lds_sh[CIN];

    const int bid = blockIdx.x;
    const int g   = bid & 3;
    const int p   = (bid >> 2) & 63;
    const int b   = bid >> 8;
    const int r0  = (p >> 3) * 32;
    const int c0  = (p & 7) * 32;
    const int tid = threadIdx.x;
    const int pg  = tid & 63;
    const int og  = tid >> 6;
    const int row = pg >> 1;
    const int xh  = pg & 1;
    const int oc4 = og * 4;

    if constexpr (L2) {
        if (tid < CIN) { lds_sc[tid] = scale_in[tid]; lds_sh[tid] = shift_in[tid]; }
    }

    const int Kst = CIN * 9;
    const float* wbase = (g < 2)
        ? (wsh + (size_t)(g * 32) * Kst)
        : (cw + (size_t)(b * 64 + p) * ATOT_ + (L2 ? A1_ : 0) + (size_t)((g - 2) * 32) * Kst);

    float acc[4][16];
    #pragma unroll
    for (int i = 0; i < 4; i++)
        #pragma unroll
        for (int j = 0; j < 16; j++) acc[i][j] = 0.0f;

    const size_t in_plane_base = ((size_t)b * CIN) * 65536;

    for (int cin0 = 0; cin0 < CIN; cin0 += CH) {
        if constexpr (L2) if (cin0 == 0) __syncthreads(); // lds_sc ready
        // ---- stage input tile 34x34 x CH (zero-pad outside image) ----
        for (int e = tid; e < CH * 34 * 34; e += 512) {
            int ix = e % 34;
            int t1 = e / 34;
            int iy = t1 % 34;
            int ic = t1 / 34;
            int gy = r0 - 1 + iy;
            int gx = c0 - 1 + ix;
            float val = 0.0f;
            if ((unsigned)gy < 256u && (unsigned)gx < 256u) {
                size_t idx = in_plane_base + (size_t)(cin0 + ic) * 65536 + gy * 256 + gx;
                if constexpr (!L2) {
                    val = xin[idx];
                } else {
                    float t = loadU(&uin[idx]);
                    val = fmaxf(fmaf(t, lds_sc[cin0 + ic], lds_sh[cin0 + ic]), 0.0f);
                }
            }
            lds_in[ic * 1224 + iy * 36 + ix] = val;
        }
        // ---- stage weights chunk: [CH][9][32oc] ----
        for (int e = tid; e < CH * 9 * 32; e += 512) {
            int oc = e & 31;
            int t1 = e >> 5;
            int kk = t1 % 9;
            int ic = t1 / 9;
            lds_w[(ic * 9 + kk) * 32 + oc] = wbase[(size_t)oc * Kst + (size_t)(cin0 + ic) * 9 + kk];
        }
        __syncthreads();

        // ---- compute: 4 oc x 16 px register tile ----
        #pragma unroll 2
        for (int ic = 0; ic < CH; ic++) {
            #pragma unroll
            for (int ky = 0; ky < 3; ky++) {
                const float* rp = &lds_in[ic * 1224 + (row + ky) * 36 + xh * 16];
                float r[20];
                *(float4*)&r[0]  = *(const float4*)&rp[0];
                *(float4*)&r[4]  = *(const float4*)&rp[4];
                *(float4*)&r[8]  = *(const float4*)&rp[8];
                *(float4*)&r[12] = *(const float4*)&rp[12];
                *(float4*)&r[16] = *(const float4*)&rp[16];
                #pragma unroll
                for (int kx = 0; kx < 3; kx++) {
                    float4 w = *(const float4*)&lds_w[(ic * 9 + ky * 3 + kx) * 32 + oc4];
                    #pragma unroll
                    for (int j = 0; j < 16; j++) {
                        float iv = r[j + kx];
                        acc[0][j] = fmaf(w.x, iv, acc[0][j]);
                        acc[1][j] = fmaf(w.y, iv, acc[1][j]);
                        acc[2][j] = fmaf(w.z, iv, acc[2][j]);
                        acc[3][j] = fmaf(w.w, iv, acc[3][j]);
                    }
                }
            }
        }
        __syncthreads();
    }

    // ---- writeback + BN partial sums ----
    #pragma unroll
    for (int i = 0; i < 4; i++) {
        int ch = g * 32 + oc4 + i;
        size_t obase = (((size_t)b * CMID_ + ch) * 256 + (r0 + row)) * 256 + c0 + xh * 16;
        if constexpr (!L2) store16(uout + obase, acc[i]);
        else               store16(vout + obase, acc[i]);

        float s = 0.0f, s2 = 0.0f;
        #pragma unroll
        for (int j = 0; j < 16; j++) { float v = acc[i][j]; s += v; s2 = fmaf(v, v, s2); }
        // wave (64-lane) butterfly reduce
        #pragma unroll
        for (int m = 32; m >= 1; m >>= 1) { s += __shfl_xor(s, m); s2 += __shfl_xor(s2, m); }
        if (pg == 0) {
            atomicAdd(&sums[ch], s);
            atomicAdd(&sums[CMID_ + ch], s2);
        }
    }
}

// ---------------- BN stats -> per-channel affine ------------------------------

__global__ void finalize_kernel(const float* __restrict__ sums,
                                const float* __restrict__ gamma,
                                const float* __restrict__ beta,
                                float* __restrict__ scale,
                                float* __restrict__ shift) {
    int c = threadIdx.x; // 128 threads
    float mean = sums[c] * (1.0f / NPX_);
    float var  = sums[128 + c] * (1.0f / NPX_) - mean * mean;
    float sc   = gamma[c] / sqrtf(var + 1e-5f);
    scale[c] = sc;
    shift[c] = fmaf(-mean, sc, beta[c]);
}

// ---------------- final BN+ReLU, in-place on d_out ---------------------------

__global__ void bnrelu_kernel(float* __restrict__ v,
                              const float* __restrict__ scale,
                              const float* __restrict__ shift) {
    const long long total4 = 16777216; // 8*128*256*256 / 4
    long long i = (long long)blockIdx.x * blockDim.x + threadIdx.x;
    long long stride = (long long)gridDim.x * blockDim.x;
    float4* p = reinterpret_cast<float4*>(v);
    for (; i < total4; i += stride) {
        int c = (int)((i >> 14) & 127); // 16384 float4 per channel plane
        float sc = scale[c], sh = shift[c];
        float4 t = p[i];
        t.x = fmaxf(fmaf(t.x, sc, sh), 0.0f);
        t.y = fmaxf(fmaf(t.y, sc, sh), 0.0f);
        t.z = fmaxf(fmaf(t.z, sc, sh), 0.0f);
        t.w = fmaxf(fmaf(t.w, sc, sh), 0.0f);
        p[i] = t;
    }
}

// ---------------- launch -----------------------------------------------------
// ws layout: [0,4096) stats floats[1024]:
//   [0..128) sum1  [128..256) sumsq1  [256..384) sum2  [384..512) sumsq2
//   [512..640) scale1 [640..768) shift1 [768..896) scale2 [896..1024) shift2
// [4096, ...) u buffer (fp32 if it fits, else bf16 fallback)

extern "C" void kernel_launch(void* const* d_in, const int* in_sizes, int n_in,
                              void* d_out, int out_size, void* d_ws, size_t ws_size,
                              hipStream_t stream) {
    const float* x  = (const float*)d_in[0];
    const float* cw = (const float*)d_in[1];
    const float* w1 = (const float*)d_in[2];
    const float* w2 = (const float*)d_in[3];
    const float* g1 = (const float*)d_in[4];
    const float* b1 = (const float*)d_in[5];
    const float* g2 = (const float*)d_in[6];
    const float* b2 = (const float*)d_in[7];
    float* out   = (float*)d_out;
    float* stats = (float*)d_ws;
    void*  u     = (char*)d_ws + 4096;

    zero_kernel<<<4, 256, 0, stream>>>(stats, 1024);

    const size_t u_f32_bytes = (size_t)8 * 128 * 256 * 256 * 4; // 256 MiB
    if (ws_size >= 4096 + u_f32_bytes) {
        conv_kernel<64, false, float><<<2048, 512, 0, stream>>>(
            x, nullptr, w1, cw, nullptr, nullptr, (float*)u, nullptr, stats);
        finalize_kernel<<<1, 128, 0, stream>>>(stats, g1, b1, stats + 512, stats + 640);
        conv_kernel<128, true, float><<<2048, 512, 0, stream>>>(
            nullptr, (const float*)u, w2, cw, stats + 512, stats + 640, nullptr, out, stats + 256);
        finalize_kernel<<<1, 128, 0, stream>>>(stats + 256, g2, b2, stats + 768, stats + 896);
        bnrelu_kernel<<<2048, 256, 0, stream>>>(out, stats + 768, stats + 896);
    } else {
        // bf16 fallback for u if workspace is small (128 MiB + stats)
        conv_kernel<64, false, __hip_bfloat16><<<2048, 512, 0, stream>>>(
            x, nullptr, w1, cw, nullptr, nullptr, (__hip_bfloat16*)u, nullptr, stats);
        finalize_kernel<<<1, 128, 0, stream>>>(stats, g1, b1, stats + 512, stats + 640);
        conv_kernel<128, true, __hip_bfloat16><<<2048, 512, 0, stream>>>(
            nullptr, (const __hip_bfloat16*)u, w2, cw, stats + 512, stats + 640, nullptr, out, stats + 256);
        finalize_kernel<<<1, 128, 0, stream>>>(stats + 256, g2, b2, stats + 768, stats + 896);
        bnrelu_kernel<<<2048, 256, 0, stream>>>(out, stats + 768, stats + 896);
    }
    (void)in_sizes; (void)n_in; (void)out_size;
}

// Round 5
// 1069.238 us; speedup vs baseline: 3.3636x; 3.3636x over previous
//
#include <hip/hip_runtime.h>
#include <hip/hip_bf16.h>
#include <cstdint>
#include <cstddef>

// Problem constants
#define A1_     36864     // 64*9*64 floats of cw1 per (b,p)
#define ATOT_   110592    // A1 + 64*9*128
#define NPX_    524288.0f // 8*256*256 elements per channel (BN stats)

typedef __attribute__((ext_vector_type(8)))  __bf16 bf16x8;
typedef __attribute__((ext_vector_type(4)))  __bf16 bf16x4;
typedef __attribute__((ext_vector_type(16))) float  f32x16;

// ---------------- zero stats (ws poisoned 0xAA each call) --------------------
__global__ void zero_kernel(float* __restrict__ p, int n) {
    int i = blockIdx.x * blockDim.x + threadIdx.x;
    if (i < n) p[i] = 0.0f;
}

// ---------------- MFMA conv: 3x3 conv = 9 accumulated GEMMs ------------------
// Grid 2048 = (b:8, p:64, ph:2 row-half, och:2). och=0: shared w1/w2 -> ch 0..63;
// och=1: per-(b,p) dynamic weights -> ch 64..127.
// Block: 64 oc x 512 px (16 rows x 32 cols). 8 waves, wave-tile 64oc x 64px
// (2 m-frags x 2 rows). MFMA v_mfma_f32_32x32x16_bf16:
//   A (weights): m=lane&31 -> oc, k=(lane>>5)*8+e -> ic   (contiguous b128)
//   B (image):   n=lane&31 -> col, k=(lane>>5)*8+e -> ic  (contiguous b128)
//   C/D: col=lane&31, row=(reg&3)+8*(reg>>2)+4*(lane>>5)  [m74/m101 verified]
// K-loop: icb over CIN/16; per icb: stage tile[18][36][16ic] bf16 + weights
// [64oc][9pair][16ic] bf16; 9 pairs x 4 MFMA. L2 applies BN+ReLU during staging.
template<int CIN, bool L2>
__global__ __launch_bounds__(512, 4) void conv_mfma(
    const float*  __restrict__ xin,   // L1 input (fp32)
    const __bf16* __restrict__ uin,   // L2 input (bf16 raw pre-BN)
    const float*  __restrict__ wsh,   // shared weights [64][CIN][3][3]
    const float*  __restrict__ cw,    // conv_weights [B][64][ATOT_]
    const float*  __restrict__ scl,   // L2: scale[128]
    const float*  __restrict__ shf,   // L2: shift[128]
    __bf16* __restrict__ uout,        // L1 output
    float*  __restrict__ vout,        // L2 output
    float*  __restrict__ sums)        // [0..128) sum, [128..256) sumsq
{
    __shared__ __bf16 tile[18 * 36 * 16];   // [y][x][ic] ic-fastest
    __shared__ __bf16 wlds[64 * 9 * 16];    // [oc][pair][ic]
    __shared__ float  lds_sc[128], lds_sh[128], lds_red[128];

    const int tid  = threadIdx.x;
    // XCD-bijective swizzle (2048 % 8 == 0): och-pairs land on same XCD L2
    const int wg   = (blockIdx.x & 7) * 256 + (blockIdx.x >> 3);
    const int och  = wg & 1;
    const int ph   = (wg >> 1) & 1;
    const int p    = (wg >> 2) & 63;
    const int b    = wg >> 8;
    const int br0  = (p >> 3) * 32 + ph * 16;  // first output row
    const int c0g  = (p & 7) * 32;             // first output col
    const int w    = tid >> 6;
    const int l    = tid & 63;
    const int ln   = l & 31;
    const int hf   = l >> 5;

    if (tid < 128) {
        lds_red[tid] = 0.0f;
        if constexpr (L2) { lds_sc[tid] = scl[tid]; lds_sh[tid] = shf[tid]; }
    }
    __syncthreads();

    const float* wbase = (och == 0)
        ? wsh
        : cw + (size_t)(b * 64 + p) * ATOT_ + (L2 ? A1_ : 0);

    f32x16 acc00, acc01, acc10, acc11;
    #pragma unroll
    for (int r = 0; r < 16; r++) { acc00[r]=0.f; acc01[r]=0.f; acc10[r]=0.f; acc11[r]=0.f; }

    for (int icb = 0; icb < CIN / 16; icb++) {
        const int cin0 = icb * 16;

        // ---- stage input tile: rows [br0-1, br0+17), cols [c0g-1, c0g+35) ----
        // tasks (y:18, icg:4, j:10): j fastest for coalescing
        for (int t = tid; t < 720; t += 512) {
            const int j   = t % 10;
            const int r2  = t / 10;
            const int icg = r2 & 3;
            const int y   = r2 >> 2;
            const int gy  = br0 - 1 + y;
            const int gx0 = c0g - 4 + 4 * j;
            const bool gyv  = (unsigned)gy < 256u;
            const bool fast = gyv && gx0 >= 0 && gx0 <= 252;
            float vv[4][4];
            #pragma unroll
            for (int i = 0; i < 4; i++) {
                const int c = cin0 + icg * 4 + i;
                float f0=0.f, f1=0.f, f2=0.f, f3=0.f;
                if constexpr (!L2) {
                    if (fast) {
                        const float4 q = *(const float4*)(xin + (((size_t)(b*CIN + c)) << 16) + gy*256 + gx0);
                        f0=q.x; f1=q.y; f2=q.z; f3=q.w;
                    } else if (gyv) {
                        const float* pl = xin + (((size_t)(b*CIN + c)) << 16) + gy*256;
                        int g;
                        g=gx0+0; if ((unsigned)g<256u) f0 = pl[g];
                        g=gx0+1; if ((unsigned)g<256u) f1 = pl[g];
                        g=gx0+2; if ((unsigned)g<256u) f2 = pl[g];
                        g=gx0+3; if ((unsigned)g<256u) f3 = pl[g];
                    }
                } else {
                    const float sc_ = lds_sc[c], sh_ = lds_sh[c];
                    if (fast) {
                        const bf16x4 q = *(const bf16x4*)(uin + (((size_t)(b*CIN + c)) << 16) + gy*256 + gx0);
                        f0 = fmaxf(fmaf((float)q[0], sc_, sh_), 0.f);
                        f1 = fmaxf(fmaf((float)q[1], sc_, sh_), 0.f);
                        f2 = fmaxf(fmaf((float)q[2], sc_, sh_), 0.f);
                        f3 = fmaxf(fmaf((float)q[3], sc_, sh_), 0.f);
                    } else if (gyv) {
                        const __bf16* pl = uin + (((size_t)(b*CIN + c)) << 16) + gy*256;
                        int g;
                        g=gx0+0; if ((unsigned)g<256u) f0 = fmaxf(fmaf((float)pl[g], sc_, sh_), 0.f);
                        g=gx0+1; if ((unsigned)g<256u) f1 = fmaxf(fmaf((float)pl[g], sc_, sh_), 0.f);
                        g=gx0+2; if ((unsigned)g<256u) f2 = fmaxf(fmaf((float)pl[g], sc_, sh_), 0.f);
                        g=gx0+3; if ((unsigned)g<256u) f3 = fmaxf(fmaf((float)pl[g], sc_, sh_), 0.f);
                    }
                }
                vv[i][0]=f0; vv[i][1]=f1; vv[i][2]=f2; vv[i][3]=f3;
            }
            #pragma unroll
            for (int jj = 0; jj < 4; jj++) {
                const int x = 4*j - 3 + jj;
                if ((unsigned)x < 36u) {
                    bf16x4 pk;
                    pk[0]=(__bf16)vv[0][jj]; pk[1]=(__bf16)vv[1][jj];
                    pk[2]=(__bf16)vv[2][jj]; pk[3]=(__bf16)vv[3][jj];
                    *(bf16x4*)&tile[((y*36) + x)*16 + icg*4] = pk;
                }
            }
        }

        // ---- stage weights: [oc][pair][ic] <- global [oc][ic][pair] ----
        // per oc: 144 contiguous floats at wbase + oc*CIN*9 + icb*144
        for (int fi = tid; fi < 2304; fi += 512) {
            const int oc = fi / 36;
            const int r4 = fi - oc * 36;
            const float4 q = *(const float4*)(wbase + (size_t)oc*(CIN*9) + icb*144 + r4*4);
            #pragma unroll
            for (int j2 = 0; j2 < 4; j2++) {
                const int lin = r4*4 + j2;
                const int ic  = lin / 9;
                const int pr  = lin - ic*9;
                const float qv = (j2==0) ? q.x : (j2==1) ? q.y : (j2==2) ? q.z : q.w;
                wlds[(oc*9 + pr)*16 + ic] = (__bf16)qv;
            }
        }
        __syncthreads();

        // ---- compute: 9 (ky,kx) pairs x 4 MFMA ----
        const int tb = ((2*w)*36 + ln)*16 + hf*8;  // tile base (n=0, ky=0, kx=0)
        const int ab = ln*144 + hf*8;               // weight base (m=0, pair=0)
        #pragma unroll
        for (int pr = 0; pr < 9; pr++) {
            const int ky = pr / 3, kx = pr - 3*ky;  // compile-time
            const bf16x8 a0 = *(const bf16x8*)&wlds[ab + pr*16];
            const bf16x8 a1 = *(const bf16x8*)&wlds[ab + 32*144 + pr*16];
            const bf16x8 b0 = *(const bf16x8*)&tile[tb + (ky*36 + kx)*16];
            const bf16x8 b1 = *(const bf16x8*)&tile[tb + (ky*36 + kx)*16 + 576];
            acc00 = __builtin_amdgcn_mfma_f32_32x32x16_bf16(a0, b0, acc00, 0, 0, 0);
            acc01 = __builtin_amdgcn_mfma_f32_32x32x16_bf16(a0, b1, acc01, 0, 0, 0);
            acc10 = __builtin_amdgcn_mfma_f32_32x32x16_bf16(a1, b0, acc10, 0, 0, 0);
            acc11 = __builtin_amdgcn_mfma_f32_32x32x16_bf16(a1, b1, acc11, 0, 0, 0);
        }
        __syncthreads();
    }

    // ---- epilogue: store + fused BN partial sums ----
    const size_t ob   = ((size_t)(b*128 + och*64)) << 16;
    const size_t rowb = (size_t)(br0 + 2*w) * 256 + c0g + ln;
    #pragma unroll
    for (int m = 0; m < 2; m++) {
        #pragma unroll
        for (int r = 0; r < 16; r++) {
            const int ocl = m*32 + (r & 3) + 8*(r >> 2) + 4*hf;
            const float v0 = (m == 0) ? acc00[r] : acc10[r];
            const float v1 = (m == 0) ? acc01[r] : acc11[r];
            const size_t adr = ob + ((size_t)ocl << 16) + rowb;
            if constexpr (!L2) { uout[adr] = (__bf16)v0; uout[adr + 256] = (__bf16)v1; }
            else               { vout[adr] = v0;         vout[adr + 256] = v1; }
            float s = v0 + v1;
            float q = v0*v0 + v1*v1;
            #pragma unroll
            for (int mk = 16; mk >= 1; mk >>= 1) {
                s += __shfl_xor(s, mk);
                q += __shfl_xor(q, mk);
            }
            if (ln == 0) {
                atomicAdd(&lds_red[ocl],      s);
                atomicAdd(&lds_red[64 + ocl], q);
            }
        }
    }
    __syncthreads();
    if (tid < 128) {
        const int oc_g = och*64 + (tid & 63);
        atomicAdd(&sums[(tid >> 6)*128 + oc_g], lds_red[tid]);
    }
}

// ---------------- BN stats -> per-channel affine -----------------------------
__global__ void finalize_kernel(const float* __restrict__ sums,
                                const float* __restrict__ gamma,
                                const float* __restrict__ beta,
                                float* __restrict__ scale,
                                float* __restrict__ shift) {
    int c = threadIdx.x; // 128
    float mean = sums[c] * (1.0f / NPX_);
    float var  = sums[128 + c] * (1.0f / NPX_) - mean * mean;
    float sc   = gamma[c] / sqrtf(var + 1e-5f);
    scale[c] = sc;
    shift[c] = fmaf(-mean, sc, beta[c]);
}

// ---------------- final BN+ReLU in-place on d_out ----------------------------
__global__ void bnrelu_kernel(float* __restrict__ v,
                              const float* __restrict__ scale,
                              const float* __restrict__ shift) {
    const long long total4 = 16777216; // 8*128*256*256 / 4
    long long i = (long long)blockIdx.x * blockDim.x + threadIdx.x;
    long long stride = (long long)gridDim.x * blockDim.x;
    float4* p = reinterpret_cast<float4*>(v);
    for (; i < total4; i += stride) {
        int c = (int)((i >> 14) & 127);
        float sc = scale[c], sh = shift[c];
        float4 t = p[i];
        t.x = fmaxf(fmaf(t.x, sc, sh), 0.0f);
        t.y = fmaxf(fmaf(t.y, sc, sh), 0.0f);
        t.z = fmaxf(fmaf(t.z, sc, sh), 0.0f);
        t.w = fmaxf(fmaf(t.w, sc, sh), 0.0f);
        p[i] = t;
    }
}

// ---------------- launch -----------------------------------------------------
// ws: [0,4096) stats: [0..128) sum1 [128..256) sq1 [256..384) sum2 [384..512) sq2
//     [512..640) sc1 [640..768) sh1 [768..896) sc2 [896..1024) sh2
// [4096, +134.2MB) u buffer (bf16 raw conv1 output)
extern "C" void kernel_launch(void* const* d_in, const int* in_sizes, int n_in,
                              void* d_out, int out_size, void* d_ws, size_t ws_size,
                              hipStream_t stream) {
    const float* x  = (const float*)d_in[0];
    const float* cw = (const float*)d_in[1];
    const float* w1 = (const float*)d_in[2];
    const float* w2 = (const float*)d_in[3];
    const float* g1 = (const float*)d_in[4];
    const float* b1 = (const float*)d_in[5];
    const float* g2 = (const float*)d_in[6];
    const float* b2 = (const float*)d_in[7];
    float*  out   = (float*)d_out;
    float*  stats = (float*)d_ws;
    __bf16* u     = (__bf16*)((char*)d_ws + 4096);

    zero_kernel<<<2, 256, 0, stream>>>(stats, 512);

    conv_mfma<64, false><<<2048, 512, 0, stream>>>(
        x, nullptr, w1, cw, nullptr, nullptr, u, nullptr, stats);
    finalize_kernel<<<1, 128, 0, stream>>>(stats, g1, b1, stats + 512, stats + 640);

    conv_mfma<128, true><<<2048, 512, 0, stream>>>(
        nullptr, u, w2, cw, stats + 512, stats + 640, nullptr, out, stats + 256);
    finalize_kernel<<<1, 128, 0, stream>>>(stats + 256, g2, b2, stats + 768, stats + 896);

    bnrelu_kernel<<<2048, 256, 0, stream>>>(out, stats + 768, stats + 896);

    (void)in_sizes; (void)n_in; (void)out_size; (void)ws_size;
}